// Round 3
// baseline (512.593 us; speedup 1.0000x reference)
//
#include <hip/hip_runtime.h>
#include <hip/hip_bf16.h>

#define NB   8
#define NTOK 1024
#define DDIM 1024
#define NEXP 16
#define HDIM 4096
#define CAP  80

using bf16x8 = __attribute__((ext_vector_type(8))) __bf16;
using f32x4  = __attribute__((ext_vector_type(4))) float;

// ---- prepass: X (fp32, rows 0..79 per sample) -> bf16, k-contiguous ----
__global__ __launch_bounds__(256) void cvt_x(
    const float* __restrict__ X, __bf16* __restrict__ Xb)
{
    int t   = blockIdx.x * 256 + threadIdx.x;   // 163840 threads, 4 elems each
    int row = t >> 8;                           // 0..639 = b*80+m
    int c4  = (t & 255) * 4;
    int b   = row / CAP;
    int m   = row - b * CAP;
    float4 v = *(const float4*)&X[(size_t)b * NTOK * DDIM + (size_t)m * DDIM + c4];
    bf16x8 dummy;
    __bf16* dst = Xb + (size_t)row * DDIM + c4;
    dst[0] = (__bf16)v.x; dst[1] = (__bf16)v.y; dst[2] = (__bf16)v.z; dst[3] = (__bf16)v.w;
    (void)dummy;
}

// ---- GEMM1 + exact GELU, barrier-free ----
// Hid[b][m][h] = gelu(sum_k Xb[b][m][k] * W1[e][k][h]), m<80.
// Block = 4 waves; wave owns one 16-col n-tile; 5 m-tiles; BK=64 per iter.
// A: direct global bf16x8 frags (L2-resident). B: fp32 global, depth-1 reg prefetch.
__global__ __launch_bounds__(256) void moe_g1(
    const __bf16* __restrict__ Xb, const int* __restrict__ Y,
    const float* __restrict__ W1, __bf16* __restrict__ Hid)
{
    const int b   = blockIdx.y;
    const int e   = Y[b] & (NEXP - 1);
    const int tid = threadIdx.x;
    const int w   = tid >> 6, l = tid & 63, q = l >> 4, r = l & 15;
    const int n   = blockIdx.x * 64 + w * 16 + r;

    const float*  Wb = W1 + (size_t)e * DDIM * HDIM + n;   // + k*HDIM
    const __bf16* Ab = Xb + (size_t)b * CAP * DDIM;        // + m*DDIM + k

    f32x4 acc[5];
    #pragma unroll
    for (int i = 0; i < 5; ++i) acc[i] = f32x4{0.f, 0.f, 0.f, 0.f};

    // prologue: B loads for k0=0
    float bcur[16];
    #pragma unroll
    for (int s = 0; s < 2; ++s)
        #pragma unroll
        for (int j = 0; j < 8; ++j)
            bcur[s * 8 + j] = Wb[(size_t)(s * 32 + q * 8 + j) * HDIM];

    #pragma unroll
    for (int k0 = 0; k0 < DDIM; k0 += 64) {
        // A fragments first (so waiting on them keeps B-prefetch in flight)
        bf16x8 af[2][5];
        #pragma unroll
        for (int s = 0; s < 2; ++s)
            #pragma unroll
            for (int mt = 0; mt < 5; ++mt)
                af[s][mt] = *(const bf16x8*)&Ab[(size_t)(mt * 16 + r) * DDIM + k0 + s * 32 + q * 8];

        // prefetch next-iter B
        float bnxt[16];
        if (k0 + 64 < DDIM) {
            const float* wp = Wb + (size_t)(k0 + 64) * HDIM;
            #pragma unroll
            for (int s = 0; s < 2; ++s)
                #pragma unroll
                for (int j = 0; j < 8; ++j)
                    bnxt[s * 8 + j] = wp[(size_t)(s * 32 + q * 8 + j) * HDIM];
        }

        bf16x8 bf[2];
        #pragma unroll
        for (int s = 0; s < 2; ++s)
            #pragma unroll
            for (int j = 0; j < 8; ++j)
                bf[s][j] = (__bf16)bcur[s * 8 + j];

        #pragma unroll
        for (int s = 0; s < 2; ++s)
            #pragma unroll
            for (int mt = 0; mt < 5; ++mt)
                acc[mt] = __builtin_amdgcn_mfma_f32_16x16x32_bf16(af[s][mt], bf[s], acc[mt], 0, 0, 0);

        if (k0 + 64 < DDIM) {
            #pragma unroll
            for (int i = 0; i < 16; ++i) bcur[i] = bnxt[i];
        }
    }

    __bf16* Hb = Hid + (size_t)b * CAP * HDIM;
    #pragma unroll
    for (int mt = 0; mt < 5; ++mt)
        #pragma unroll
        for (int v = 0; v < 4; ++v) {
            int m = mt * 16 + q * 4 + v;
            float x = acc[mt][v];
            float g = 0.5f * x * (1.0f + erff(x * 0.70710678118654752f));
            Hb[(size_t)m * HDIM + n] = (__bf16)g;
        }
}

// ---- GEMM2, barrier-free, split-K=4, atomic fp32 into zeroed Out ----
__global__ __launch_bounds__(256) void moe_g2(
    const __bf16* __restrict__ Hid, const int* __restrict__ Y,
    const float* __restrict__ W2, float* __restrict__ Out)
{
    const int b   = blockIdx.y;
    const int e   = Y[b] & (NEXP - 1);
    const int kz  = blockIdx.z * (HDIM / 4);
    const int tid = threadIdx.x;
    const int w   = tid >> 6, l = tid & 63, q = l >> 4, r = l & 15;
    const int n   = blockIdx.x * 64 + w * 16 + r;

    const float*  Wb = W2  + (size_t)e * HDIM * DDIM + n;  // + k*DDIM
    const __bf16* Ab = Hid + (size_t)b * CAP * HDIM;       // + m*HDIM + k

    f32x4 acc[5];
    #pragma unroll
    for (int i = 0; i < 5; ++i) acc[i] = f32x4{0.f, 0.f, 0.f, 0.f};

    float bcur[16];
    #pragma unroll
    for (int s = 0; s < 2; ++s)
        #pragma unroll
        for (int j = 0; j < 8; ++j)
            bcur[s * 8 + j] = Wb[(size_t)(kz + s * 32 + q * 8 + j) * DDIM];

    #pragma unroll
    for (int kk = 0; kk < HDIM / 4; kk += 64) {
        const int k0 = kz + kk;
        bf16x8 af[2][5];
        #pragma unroll
        for (int s = 0; s < 2; ++s)
            #pragma unroll
            for (int mt = 0; mt < 5; ++mt)
                af[s][mt] = *(const bf16x8*)&Ab[(size_t)(mt * 16 + r) * HDIM + k0 + s * 32 + q * 8];

        float bnxt[16];
        if (kk + 64 < HDIM / 4) {
            const float* wp = Wb + (size_t)(k0 + 64) * DDIM;
            #pragma unroll
            for (int s = 0; s < 2; ++s)
                #pragma unroll
                for (int j = 0; j < 8; ++j)
                    bnxt[s * 8 + j] = wp[(size_t)(s * 32 + q * 8 + j) * DDIM];
        }

        bf16x8 bf[2];
        #pragma unroll
        for (int s = 0; s < 2; ++s)
            #pragma unroll
            for (int j = 0; j < 8; ++j)
                bf[s][j] = (__bf16)bcur[s * 8 + j];

        #pragma unroll
        for (int s = 0; s < 2; ++s)
            #pragma unroll
            for (int mt = 0; mt < 5; ++mt)
                acc[mt] = __builtin_amdgcn_mfma_f32_16x16x32_bf16(af[s][mt], bf[s], acc[mt], 0, 0, 0);

        if (kk + 64 < HDIM / 4) {
            #pragma unroll
            for (int i = 0; i < 16; ++i) bcur[i] = bnxt[i];
        }
    }

    float* Ob = Out + (size_t)b * NTOK * DDIM;
    #pragma unroll
    for (int mt = 0; mt < 5; ++mt)
        #pragma unroll
        for (int v = 0; v < 4; ++v) {
            int m = mt * 16 + q * 4 + v;
            atomicAdd(&Ob[(size_t)m * DDIM + n], acc[mt][v]);
        }
}

extern "C" void kernel_launch(void* const* d_in, const int* in_sizes, int n_in,
                              void* d_out, int out_size, void* d_ws, size_t ws_size,
                              hipStream_t stream) {
    const float* X  = (const float*)d_in[0];
    const int*   Y  = (const int*)d_in[1];
    const float* W1 = (const float*)d_in[2];
    const float* W2 = (const float*)d_in[3];
    float*  Out = (float*)d_out;
    __bf16* Xb  = (__bf16*)d_ws;                                   // 1.31 MB
    __bf16* Hid = (__bf16*)((char*)d_ws + (2u << 20));             // 5.24 MB

    hipMemsetAsync(d_out, 0, (size_t)out_size * sizeof(float), stream);
    cvt_x<<<dim3(640), 256, 0, stream>>>(X, Xb);
    moe_g1<<<dim3(HDIM / 64, NB), 256, 0, stream>>>(Xb, Y, W1, Hid);
    moe_g2<<<dim3(DDIM / 64, NB, 4), 256, 0, stream>>>(Hid, Y, W2, Out);
}